// Round 3
// baseline (139.053 us; speedup 1.0000x reference)
//
#include <hip/hip_runtime.h>
#include <math.h>

// Chamfer distance on MI355X (gfx950).  B=8, N=M=8192, fp32.
// out = concat(dist1[B*N], dist2[B*M]).
//
// Round 3: same 3.5-VALU-op/pair inner loop (3 FMAs seeded with |c|^2 via
// (-2x,-2y,-2z,|c|^2) candidates + v_min3 over candidate pairs), but:
//  - Q=16 queries/thread (was 8): halves LDS ds_read_b128 per VALU op and
//    halves block count (half the exposed prologues).
//  - Precompute kernel writes both point sets as float4 (-2x,-2y,-2z,|c|^2)
//    into d_ws; main kernel stages candidates with one coalesced dwordx4 +
//    ds_write_b128 (no transform math) and loads queries as 16 coalesced
//    dwordx4 (plain coords recovered via *-0.5; |q|^2 recomputed at epilogue).
//  - grid = 2 x 32 x 16 = 1024 blocks = 4 blocks/CU = 16 waves/CU.
// Partial minima merged with uint atomicMin (valid for non-negative floats);
// d_out pre-set to 0x7f7f7f7f each call.

#define BLOCK 256
#define Q 16
#define QB (BLOCK * Q)   // 4096 queries per block
#define CT 256           // candidates per block tile (4 KB of float4 in LDS)

__global__ __launch_bounds__(BLOCK) void chamfer_pre(
    const float* __restrict__ xyz1, const float* __restrict__ xyz2,
    float4* __restrict__ c1, float4* __restrict__ c2, int P1, int P2)
{
    const int t = blockIdx.x * BLOCK + threadIdx.x;
    if (t < P1) {
        const float x = xyz1[3 * t + 0];
        const float y = xyz1[3 * t + 1];
        const float z = xyz1[3 * t + 2];
        const float sq = fmaf(x, x, fmaf(y, y, z * z));
        c1[t] = make_float4(-2.f * x, -2.f * y, -2.f * z, sq);
    }
    if (t < P2) {
        const float x = xyz2[3 * t + 0];
        const float y = xyz2[3 * t + 1];
        const float z = xyz2[3 * t + 2];
        const float sq = fmaf(x, x, fmaf(y, y, z * z));
        c2[t] = make_float4(-2.f * x, -2.f * y, -2.f * z, sq);
    }
}

template <bool PRE>
__global__ __launch_bounds__(BLOCK, 4) void chamfer_main(
    const float* __restrict__ xyz1, const float* __restrict__ xyz2,
    const float4* __restrict__ c1, const float4* __restrict__ c2,
    float* __restrict__ out, int B, int N, int M)
{
    const int z   = blockIdx.z;      // [0, 2*B)
    const int dir = z / B;           // 0: queries=set1, cands=set2 ; 1: swapped
    const int b   = z % B;

    const float*  qpr; const float*  cpr;
    const float4* qp4; const float4* cp4;
    float* o; int Nq, Nc;
    if (dir == 0) {
        Nq = N; Nc = M;
        qpr = xyz1 + (size_t)b * N * 3;  cpr = xyz2 + (size_t)b * M * 3;
        qp4 = c1 + (size_t)b * N;        cp4 = c2 + (size_t)b * M;
        o   = out + (size_t)b * N;
    } else {
        Nq = M; Nc = N;
        qpr = xyz2 + (size_t)b * M * 3;  cpr = xyz1 + (size_t)b * N * 3;
        qp4 = c2 + (size_t)b * M;        cp4 = c1 + (size_t)b * N;
        o   = out + (size_t)B * N + (size_t)b * M;
    }

    // ---- stage candidate tile (-2x,-2y,-2z,|c|^2) into LDS ----
    __shared__ float4 sc[CT];
    const int c0 = blockIdx.y * CT;
    {
        const int i = threadIdx.x;           // CT == BLOCK: one element each
        const int j = c0 + i;
        float4 v = make_float4(0.f, 0.f, 0.f, 3.0e38f);  // OOB -> far away
        if (j < Nc) {
            if (PRE) {
                v = cp4[j];
            } else {
                const float x = cpr[3 * j + 0];
                const float y = cpr[3 * j + 1];
                const float zz = cpr[3 * j + 2];
                v = make_float4(-2.f * x, -2.f * y, -2.f * zz,
                                fmaf(x, x, fmaf(y, y, zz * zz)));
            }
        }
        sc[i] = v;
    }
    __syncthreads();

    // ---- load Q queries per thread into registers (plain coords) ----
    const int n0 = blockIdx.x * QB + threadIdx.x;
    float qx[Q], qy[Q], qz[Q], mm[Q];
#pragma unroll
    for (int q = 0; q < Q; ++q) {
        const int n  = n0 + q * BLOCK;
        const int nn = (n < Nq) ? n : (Nq - 1);   // clamp; result discarded
        if (PRE) {
            const float4 v = qp4[nn];             // coalesced dwordx4
            qx[q] = -0.5f * v.x; qy[q] = -0.5f * v.y; qz[q] = -0.5f * v.z;
        } else {
            qx[q] = qpr[3 * nn + 0];
            qy[q] = qpr[3 * nn + 1];
            qz[q] = qpr[3 * nn + 2];
        }
        mm[q] = 3.0e38f;
    }

    // ---- main scan: per (query, 2 candidates): 6 FMA + 1 min3 ----
#pragma unroll 2
    for (int j = 0; j < CT; j += 2) {
        const float4 ca = sc[j];       // wave-uniform address -> LDS broadcast
        const float4 cb = sc[j + 1];
#pragma unroll
        for (int q = 0; q < Q; ++q) {
            float t0 = fmaf(qx[q], ca.x, ca.w);
            t0 = fmaf(qy[q], ca.y, t0);
            t0 = fmaf(qz[q], ca.z, t0);
            float t1 = fmaf(qx[q], cb.x, cb.w);
            t1 = fmaf(qy[q], cb.y, t1);
            t1 = fmaf(qz[q], cb.z, t1);
            mm[q] = fminf(fminf(t0, t1), mm[q]);   // -> v_min3_f32
        }
    }

    // ---- epilogue: add |q|^2, clamp, merge partial min via uint atomicMin ----
#pragma unroll
    for (int q = 0; q < Q; ++q) {
        const int n = n0 + q * BLOCK;
        if (n < Nq) {
            float sq1 = qx[q] * qx[q];
            sq1 = fmaf(qy[q], qy[q], sq1);
            sq1 = fmaf(qz[q], qz[q], sq1);
            const float d = fmaxf(sq1 + mm[q], 0.0f);
            atomicMin((unsigned int*)(o + n), __float_as_uint(d));
        }
    }
}

extern "C" void kernel_launch(void* const* d_in, const int* in_sizes, int n_in,
                              void* d_out, int out_size, void* d_ws, size_t ws_size,
                              hipStream_t stream) {
    const float* xyz1 = (const float*)d_in[0];
    const float* xyz2 = (const float*)d_in[1];
    float* out = (float*)d_out;

    const int B = 8;                      // fixed by the reference problem
    const int N = in_sizes[0] / (B * 3);  // 8192
    const int M = in_sizes[1] / (B * 3);  // 8192
    const int P1 = B * N, P2 = B * M;

    // Initialize outputs to a huge positive float (0x7f7f7f7f) so uint
    // atomicMin of non-negative distances always wins.
    hipMemsetAsync(d_out, 0x7f, (size_t)out_size * sizeof(float), stream);

    const size_t ws_need = (size_t)(P1 + P2) * sizeof(float4);
    const bool pre = (ws_size >= ws_need);
    float4* c1 = (float4*)d_ws;
    float4* c2 = c1 + P1;

    const int nmax = (N > M) ? N : M;
    dim3 grid((nmax + QB - 1) / QB,          // query chunks (2)
              (nmax + CT - 1) / CT,          // candidate splits (32)
              2 * B);                        // direction x batch (16)

    if (pre) {
        const int pmax = (P1 > P2) ? P1 : P2;
        chamfer_pre<<<(pmax + BLOCK - 1) / BLOCK, dim3(BLOCK), 0, stream>>>(
            xyz1, xyz2, c1, c2, P1, P2);
        chamfer_main<true><<<grid, dim3(BLOCK), 0, stream>>>(
            xyz1, xyz2, c1, c2, out, B, N, M);
    } else {
        chamfer_main<false><<<grid, dim3(BLOCK), 0, stream>>>(
            xyz1, xyz2, c1, c2, out, B, N, M);
    }
}

// Round 4
// 135.809 us; speedup vs baseline: 1.0239x; 1.0239x over previous
//
#include <hip/hip_runtime.h>
#include <math.h>

// Chamfer distance on MI355X (gfx950).  B=8, N=M=8192, fp32.
// out = concat(dist1[B*N], dist2[B*M]).
//
// Round 4: R3's instruction mix (Q=16: 2 ds_read_b128 per 112 VALU ops ->
// LDS pipe ~43% vs 86% at Q=8) combined with R2's parallelism (2048 blocks
// = 8 blocks/CU = 32 waves/CU; CT 256->128 doubles candidate splits).
// Inner loop unchanged: 3.5 VALU ops/pair — 3 chained FMAs seeded with |c|^2
// via precomputed (-2x,-2y,-2z,|c|^2) candidates, v_min3 over candidate pairs.
// Partial minima merged with uint atomicMin (valid for non-negative floats);
// d_out pre-set to 0x7f7f7f7f each call.

#define BLOCK 256
#define Q 16
#define QB (BLOCK * Q)   // 4096 queries per block
#define CT 128           // candidates per block tile (2 KB of float4 in LDS)

__global__ __launch_bounds__(BLOCK) void chamfer_pre(
    const float* __restrict__ xyz1, const float* __restrict__ xyz2,
    float4* __restrict__ c1, float4* __restrict__ c2, int P1, int P2)
{
    const int t = blockIdx.x * BLOCK + threadIdx.x;
    if (t < P1) {
        const float x = xyz1[3 * t + 0];
        const float y = xyz1[3 * t + 1];
        const float z = xyz1[3 * t + 2];
        const float sq = fmaf(x, x, fmaf(y, y, z * z));
        c1[t] = make_float4(-2.f * x, -2.f * y, -2.f * z, sq);
    }
    if (t < P2) {
        const float x = xyz2[3 * t + 0];
        const float y = xyz2[3 * t + 1];
        const float z = xyz2[3 * t + 2];
        const float sq = fmaf(x, x, fmaf(y, y, z * z));
        c2[t] = make_float4(-2.f * x, -2.f * y, -2.f * z, sq);
    }
}

template <bool PRE>
__global__ __launch_bounds__(BLOCK, 4) void chamfer_main(
    const float* __restrict__ xyz1, const float* __restrict__ xyz2,
    const float4* __restrict__ c1, const float4* __restrict__ c2,
    float* __restrict__ out, int B, int N, int M)
{
    const int z   = blockIdx.z;      // [0, 2*B)
    const int dir = z / B;           // 0: queries=set1, cands=set2 ; 1: swapped
    const int b   = z % B;

    const float*  qpr; const float*  cpr;
    const float4* qp4; const float4* cp4;
    float* o; int Nq, Nc;
    if (dir == 0) {
        Nq = N; Nc = M;
        qpr = xyz1 + (size_t)b * N * 3;  cpr = xyz2 + (size_t)b * M * 3;
        qp4 = c1 + (size_t)b * N;        cp4 = c2 + (size_t)b * M;
        o   = out + (size_t)b * N;
    } else {
        Nq = M; Nc = N;
        qpr = xyz2 + (size_t)b * M * 3;  cpr = xyz1 + (size_t)b * N * 3;
        qp4 = c2 + (size_t)b * M;        cp4 = c1 + (size_t)b * N;
        o   = out + (size_t)B * N + (size_t)b * M;
    }

    // ---- stage candidate tile (-2x,-2y,-2z,|c|^2) into LDS ----
    __shared__ float4 sc[CT];
    const int c0 = blockIdx.y * CT;
    if (threadIdx.x < CT) {
        const int i = threadIdx.x;
        const int j = c0 + i;
        float4 v = make_float4(0.f, 0.f, 0.f, 3.0e38f);  // OOB -> far away
        if (j < Nc) {
            if (PRE) {
                v = cp4[j];
            } else {
                const float x = cpr[3 * j + 0];
                const float y = cpr[3 * j + 1];
                const float zz = cpr[3 * j + 2];
                v = make_float4(-2.f * x, -2.f * y, -2.f * zz,
                                fmaf(x, x, fmaf(y, y, zz * zz)));
            }
        }
        sc[i] = v;
    }
    __syncthreads();

    // ---- load Q queries per thread into registers (plain coords) ----
    const int n0 = blockIdx.x * QB + threadIdx.x;
    float qx[Q], qy[Q], qz[Q], mm[Q];
#pragma unroll
    for (int q = 0; q < Q; ++q) {
        const int n  = n0 + q * BLOCK;
        const int nn = (n < Nq) ? n : (Nq - 1);   // clamp; result discarded
        if (PRE) {
            const float4 v = qp4[nn];             // coalesced dwordx4
            qx[q] = -0.5f * v.x; qy[q] = -0.5f * v.y; qz[q] = -0.5f * v.z;
        } else {
            qx[q] = qpr[3 * nn + 0];
            qy[q] = qpr[3 * nn + 1];
            qz[q] = qpr[3 * nn + 2];
        }
        mm[q] = 3.0e38f;
    }

    // ---- main scan: per (query, 2 candidates): 6 FMA + 1 min3 ----
#pragma unroll 2
    for (int j = 0; j < CT; j += 2) {
        const float4 ca = sc[j];       // wave-uniform address -> LDS broadcast
        const float4 cb = sc[j + 1];
#pragma unroll
        for (int q = 0; q < Q; ++q) {
            float t0 = fmaf(qx[q], ca.x, ca.w);
            t0 = fmaf(qy[q], ca.y, t0);
            t0 = fmaf(qz[q], ca.z, t0);
            float t1 = fmaf(qx[q], cb.x, cb.w);
            t1 = fmaf(qy[q], cb.y, t1);
            t1 = fmaf(qz[q], cb.z, t1);
            mm[q] = fminf(fminf(t0, t1), mm[q]);   // -> v_min3_f32
        }
    }

    // ---- epilogue: add |q|^2, clamp, merge partial min via uint atomicMin ----
#pragma unroll
    for (int q = 0; q < Q; ++q) {
        const int n = n0 + q * BLOCK;
        if (n < Nq) {
            float sq1 = qx[q] * qx[q];
            sq1 = fmaf(qy[q], qy[q], sq1);
            sq1 = fmaf(qz[q], qz[q], sq1);
            const float d = fmaxf(sq1 + mm[q], 0.0f);
            atomicMin((unsigned int*)(o + n), __float_as_uint(d));
        }
    }
}

extern "C" void kernel_launch(void* const* d_in, const int* in_sizes, int n_in,
                              void* d_out, int out_size, void* d_ws, size_t ws_size,
                              hipStream_t stream) {
    const float* xyz1 = (const float*)d_in[0];
    const float* xyz2 = (const float*)d_in[1];
    float* out = (float*)d_out;

    const int B = 8;                      // fixed by the reference problem
    const int N = in_sizes[0] / (B * 3);  // 8192
    const int M = in_sizes[1] / (B * 3);  // 8192
    const int P1 = B * N, P2 = B * M;

    // Initialize outputs to a huge positive float (0x7f7f7f7f) so uint
    // atomicMin of non-negative distances always wins.
    hipMemsetAsync(d_out, 0x7f, (size_t)out_size * sizeof(float), stream);

    const size_t ws_need = (size_t)(P1 + P2) * sizeof(float4);
    const bool pre = (ws_size >= ws_need);
    float4* c1 = (float4*)d_ws;
    float4* c2 = c1 + P1;

    const int nmax = (N > M) ? N : M;
    dim3 grid((nmax + QB - 1) / QB,          // query chunks (2)
              (nmax + CT - 1) / CT,          // candidate splits (64)
              2 * B);                        // direction x batch (16)
    // 2 x 64 x 16 = 2048 blocks = 8 blocks/CU (VGPR ~56 -> 32 waves/CU fit)

    if (pre) {
        const int pmax = (P1 > P2) ? P1 : P2;
        chamfer_pre<<<(pmax + BLOCK - 1) / BLOCK, dim3(BLOCK), 0, stream>>>(
            xyz1, xyz2, c1, c2, P1, P2);
        chamfer_main<true><<<grid, dim3(BLOCK), 0, stream>>>(
            xyz1, xyz2, c1, c2, out, B, N, M);
    } else {
        chamfer_main<false><<<grid, dim3(BLOCK), 0, stream>>>(
            xyz1, xyz2, c1, c2, out, B, N, M);
    }
}